// Round 12
// baseline (790.666 us; speedup 1.0000x reference)
//
#include <hip/hip_runtime.h>
#include <math.h>

#define NN 100000
#define EE 1600000
#define NBLK_SCAN 256
#define CHUNK ((NN + NBLK_SCAN - 1) / NBLK_SCAN)   // 391

typedef __attribute__((ext_vector_type(8))) short bf16x8;
typedef __attribute__((ext_vector_type(4))) float f32x4;

__device__ __forceinline__ ushort f2bf(float x) {
    uint u = __builtin_bit_cast(uint, x);
    u += 0x7fffu + ((u >> 16) & 1u);   // RNE
    return (ushort)(u >> 16);
}
__device__ __forceinline__ float bf2f(ushort u) {
    uint v = ((uint)u) << 16;
    return __builtin_bit_cast(float, v);
}

// ---------------- embed: h_emb = h @ emb_W + emb_b  (bf16 output) ----------------
__global__ __launch_bounds__(256) void embed_kernel(
    const float* __restrict__ h, const float* __restrict__ embW,
    const float* __restrict__ embB, ushort* __restrict__ hembb)
{
    int t = blockIdx.x * 256 + threadIdx.x;
    int n = t >> 6;
    int j = t & 63;
    if (n >= NN) return;
    float acc = embB[j];
#pragma unroll
    for (int k = 0; k < 16; ++k)
        acc = fmaf(h[n * 16 + k], embW[k * 64 + j], acc);
    hembb[n * 64 + j] = f2bf(acc);
}

// ---------------- sort: histogram ----------------
__global__ __launch_bounds__(256) void hist_kernel(
    const int* __restrict__ ei, int* __restrict__ hist)
{
    for (int e = blockIdx.x * 256 + threadIdx.x; e < EE; e += gridDim.x * 256)
        atomicAdd(&hist[ei[e]], 1);
}

// ---------------- sort: scan (3 kernels) ----------------
__global__ __launch_bounds__(256) void scan_a(const int* __restrict__ hist, int* __restrict__ bsum)
{
    __shared__ int red[256];
    const int b = blockIdx.x, t = threadIdx.x;
    const int start = b * CHUNK, end = min(NN, start + CHUNK);
    int s = 0;
    for (int i = start + t; i < end; i += 256) s += hist[i];
    red[t] = s; __syncthreads();
    for (int k = 128; k > 0; k >>= 1) { if (t < k) red[t] += red[t + k]; __syncthreads(); }
    if (t == 0) bsum[b] = red[0];
}

__global__ void scan_b(const int* __restrict__ bsum, int* __restrict__ boff)
{
    if (threadIdx.x == 0) {
        int acc = 0;
        for (int i = 0; i < NBLK_SCAN; ++i) { boff[i] = acc; acc += bsum[i]; }
    }
}

__global__ __launch_bounds__(256) void scan_c(
    const int* __restrict__ hist, const int* __restrict__ boff,
    int* __restrict__ csr, int* __restrict__ cursor)
{
    __shared__ int lds[CHUNK];
    const int b = blockIdx.x, t = threadIdx.x;
    const int start = b * CHUNK, end = min(NN, start + CHUNK), n = end - start;
    for (int i = t; i < n; i += 256) lds[i] = hist[start + i];
    __syncthreads();
    if (t == 0) {
        int acc = boff[b];
        for (int i = 0; i < n; ++i) { int v = lds[i]; lds[i] = acc; acc += v; }
        if (end == NN) csr[NN] = acc;   // == EE
    }
    __syncthreads();
    for (int i = t; i < n; i += 256) { csr[start + i] = lds[i]; cursor[start + i] = lds[i]; }
}

// ---------------- sort: scatter sorted (row,col) pairs ----------------
__global__ __launch_bounds__(256) void scatter_kernel(
    const int* __restrict__ ei, int* __restrict__ cursor, int2* __restrict__ srt)
{
    for (int e = blockIdx.x * 256 + threadIdx.x; e < EE; e += gridDim.x * 256) {
        const int row = ei[e];
        const int p = atomicAdd(&cursor[row], 1);
        srt[p] = make_int2(row, ei[EE + e]);
    }
}

// ---------------- edge kernel: MFMA edge MLP + w-MLP, software-pipelined ----------------
// 1000 blocks x 4 waves (256 thr); each wave owns 400 sorted positions (25 batches of 16).
// Occupancy model (r5-r11 measured): __launch_bounds__ 2nd arg = min waves/EU on the
//   UNIFIED VGPR+AGPR file (512/SIMD): cap = 512/arg. (512,2)->256 (128 arch+128 agpr),
//   (512,4)->128 (SPILLS). 512-thread blocks quantize residency to 2 waves/SIMD, so r12
//   uses 256-thread blocks (quantum = 1 wave/SIMD) + (256,3) -> ~170 unified -> 3 waves/SIMD.
//   Spill sentinel: FETCH_SIZE (~105-120 MB clean; >300 MB = spilled).
// cvt_pk asm REVERTED (r11 correctness failure: absmax 10.5 — unverified operand order).
// LDS/block: 32 KB weights + 4x2560B scratch + 2 KB scal = 45 KB -> 3 blocks/CU fit.
// MFMA layout (mfma_f32_16x16x32_bf16):
//   A frag: lane l holds A[l&15][(l>>4)*8 + b]
//   B frag: lane l holds B[(l>>4)*8 + b][l&15]
//   D:      lane l, reg r holds D[(l>>4)*4 + r][l&15]
// Activation LDS is k-permuted: storage s holds column j(s) = (s>>2) + (s&3)*16.
__global__ __launch_bounds__(256, 3) void edge_kernel(
    const ushort* __restrict__ hembb, const float* __restrict__ x,
    const int2* __restrict__ srt,
    const float* __restrict__ eW1, const float* __restrict__ eb1,
    const float* __restrict__ eW2, const float* __restrict__ eb2,
    const float* __restrict__ wW1, const float* __restrict__ wb1,
    const float* __restrict__ wW2, const float* __restrict__ wb2,
    float* __restrict__ agg, float* __restrict__ vsum)
{
    // B-fragments: 32 frags x (64 lanes x 8 ush) = 32 KB
    //   frags 0..15 : eW1 ; 16..23: eW2 ; 24..31: wW1
    __shared__ ushort sWB[32 * 512];
    __shared__ ushort sS[4][1280];          // per-wave scratch: T1 then EF (overlaid)
    __shared__ float  sScal[4][2][16][4];   // ping-pong {rd, rd*c2, rd*s2, rd*phi}

    const int tid = threadIdx.x;
    const int wave = tid >> 6, lane = tid & 63;
    const int l15 = lane & 15, g = lane >> 4;

    // ---- one-time weight staging into LDS (split across 4 waves) ----
#pragma unroll
    for (int q = 0; q < 4; ++q) {
        const int fi = wave * 4 + q;           // 0..15
        const int kc = fi >> 2, t = fi & 3;
        bf16x8 f;
#pragma unroll
        for (int b = 0; b < 8; ++b)
            f[b] = (short)f2bf(eW1[(kc * 32 + g * 8 + b) * 64 + t * 16 + l15]);
        *(bf16x8*)&sWB[fi * 512 + lane * 8] = f;
    }
#pragma unroll
    for (int q = 0; q < 2; ++q) {
        const int fi = wave * 2 + q;           // 0..7
        const int kc = fi >> 2, t = fi & 3;
        bf16x8 f, fv;
#pragma unroll
        for (int b = 0; b < 8; ++b) {
            int s = kc * 32 + g * 8 + b;
            int j = (s >> 2) + (s & 3) * 16;   // permuted k
            f[b]  = (short)f2bf(eW2[j * 64 + t * 16 + l15]);
            fv[b] = (short)f2bf(wW1[j * 64 + t * 16 + l15]);
        }
        *(bf16x8*)&sWB[(16 + fi) * 512 + lane * 8] = f;
        *(bf16x8*)&sWB[(24 + fi) * 512 + lane * 8] = fv;
    }

    float b1v[4], b2v[4], wb1v[4], w2v[4], w128v[4];
#pragma unroll
    for (int t = 0; t < 4; ++t) {
        b1v[t]   = eb1[t * 16 + l15];
        b2v[t]   = eb2[t * 16 + l15];
        wb1v[t]  = wb1[t * 16 + l15];
        w2v[t]   = wW2[t * 16 + l15];
        w128v[t] = eW1[128 * 64 + t * 16 + l15];
    }
    const float wb2v = wb2[0];
    __syncthreads();   // weights visible to all waves; no block barriers after this

    ushort* SC = sS[wave];
    const int base = (blockIdx.x * 4 + wave) * 400;

    float carry = 0.f, carryv = 0.f;
    int cur_row = -1;

    // ---- prologue: batch 0 prepared; batch 1 srt prefetched ----
    int rowv = 0;
    {
        int colv = 0;
        if (lane < 16) {
            const int2 rc = srt[base + lane];
            rowv = rc.x; colv = rc.y;
            const float dx = x[rowv * 3 + 0] - x[colv * 3 + 0];
            const float dy = x[rowv * 3 + 1] - x[colv * 3 + 1];
            const float dz = x[rowv * 3 + 2] - x[colv * 3 + 2];
            const float r2 = dx * dx + dy * dy;
            const float rdv = r2 + dz * dz;
            const float inv = (r2 > 0.f) ? (1.f / r2) : 0.f;
            const float c2  = (r2 > 0.f) ? ((dx * dx - dy * dy) * inv) : 1.f;
            const float sn2 = 2.f * dx * dy * inv;
            const float phi = atan2f(dz, sqrtf(r2));
            float4 sc = {rdv, rdv * c2, rdv * sn2, rdv * phi};
            *(float4*)&sScal[wave][0][lane][0] = sc;
        }
    }
    bf16x8 a0, a1, a2, a3;
    {
        int colv0 = 0;
        if (lane < 16) colv0 = srt[base + lane].y;   // L2-hot reload
        const int rowN = __shfl(rowv, l15);
        const int colN = __shfl(colv0, l15);
        a0 = *(const bf16x8*)&hembb[(size_t)rowN * 64 + g * 8];
        a1 = *(const bf16x8*)&hembb[(size_t)rowN * 64 + 32 + g * 8];
        a2 = *(const bf16x8*)&hembb[(size_t)colN * 64 + g * 8];
        a3 = *(const bf16x8*)&hembb[(size_t)colN * 64 + 32 + g * 8];
    }
    int2 rc2 = make_int2(0, 0);
    if (lane < 16) rc2 = srt[min(base + 16 + lane, EE - 1)];

    int buf = 0;

    for (int bt = 0; bt < 25; ++bt) {
        // ---- step 0: srt prefetch for bt+2 ----
        int2 rc3 = make_int2(0, 0);
        if (lane < 16) rc3 = srt[min(base + (bt + 2) * 16 + lane, EE - 1)];

        // ---- step 1: layer 1 (uses a0..a3, sScal[buf]) ----
        f32x4 acc[4];
#pragma unroll
        for (int t = 0; t < 4; ++t) acc[t] = (f32x4){b1v[t], b1v[t], b1v[t], b1v[t]};
#pragma unroll
        for (int t = 0; t < 4; ++t) {
            acc[t] = __builtin_amdgcn_mfma_f32_16x16x32_bf16(
                a0, *(const bf16x8*)&sWB[(0 * 4 + t) * 512 + lane * 8], acc[t], 0, 0, 0);
            acc[t] = __builtin_amdgcn_mfma_f32_16x16x32_bf16(
                a1, *(const bf16x8*)&sWB[(1 * 4 + t) * 512 + lane * 8], acc[t], 0, 0, 0);
            acc[t] = __builtin_amdgcn_mfma_f32_16x16x32_bf16(
                a2, *(const bf16x8*)&sWB[(2 * 4 + t) * 512 + lane * 8], acc[t], 0, 0, 0);
            acc[t] = __builtin_amdgcn_mfma_f32_16x16x32_bf16(
                a3, *(const bf16x8*)&sWB[(3 * 4 + t) * 512 + lane * 8], acc[t], 0, 0, 0);
        }
#pragma unroll
        for (int r = 0; r < 4; ++r) {
            const float rd_r = sScal[wave][buf][g * 4 + r][0];
#pragma unroll
            for (int t = 0; t < 4; ++t) acc[t][r] = fmaf(rd_r, w128v[t], acc[t][r]);
        }
        // relu + pack to T1 (permuted storage s = c*4 + t)
#pragma unroll
        for (int r = 0; r < 4; ++r) {
            const float v0 = fmaxf(acc[0][r], 0.f), v1 = fmaxf(acc[1][r], 0.f);
            const float v2 = fmaxf(acc[2][r], 0.f), v3 = fmaxf(acc[3][r], 0.f);
            uint2 p;
            p.x = (uint)f2bf(v0) | ((uint)f2bf(v1) << 16);
            p.y = (uint)f2bf(v2) | ((uint)f2bf(v3) << 16);
            *(uint2*)&SC[(g * 4 + r) * 80 + l15 * 4] = p;
        }

        // ---- step 2: issue next batch's gathers (A-frags + x) ----
        const int rv2 = rc2.x, cv2 = rc2.y;          // valid on lanes 0..15
        const int rowN2 = __shfl(rv2, l15);
        const int colN2 = __shfl(cv2, l15);
        const bf16x8 n0 = *(const bf16x8*)&hembb[(size_t)rowN2 * 64 + g * 8];
        const bf16x8 n1 = *(const bf16x8*)&hembb[(size_t)rowN2 * 64 + 32 + g * 8];
        const bf16x8 n2 = *(const bf16x8*)&hembb[(size_t)colN2 * 64 + g * 8];
        const bf16x8 n3 = *(const bf16x8*)&hembb[(size_t)colN2 * 64 + 32 + g * 8];
        float xr0 = 0.f, xr1 = 0.f, xr2 = 0.f, xc0 = 0.f, xc1 = 0.f, xc2 = 0.f;
        if (lane < 16) {
            xr0 = x[rv2 * 3 + 0]; xr1 = x[rv2 * 3 + 1]; xr2 = x[rv2 * 3 + 2];
            xc0 = x[cv2 * 3 + 0]; xc1 = x[cv2 * 3 + 1]; xc2 = x[cv2 * 3 + 2];
        }

        // ---- step 3: layer 2 (T1 -> EF, EF overlays T1) ----
        f32x4 acc2[4];
#pragma unroll
        for (int t = 0; t < 4; ++t) acc2[t] = (f32x4){b2v[t], b2v[t], b2v[t], b2v[t]};
#pragma unroll
        for (int kc = 0; kc < 2; ++kc) {
            bf16x8 a = *(const bf16x8*)&SC[l15 * 80 + kc * 32 + g * 8];
#pragma unroll
            for (int t = 0; t < 4; ++t)
                acc2[t] = __builtin_amdgcn_mfma_f32_16x16x32_bf16(
                    a, *(const bf16x8*)&sWB[(16 + kc * 4 + t) * 512 + lane * 8], acc2[t], 0, 0, 0);
        }
#pragma unroll
        for (int r = 0; r < 4; ++r) {
            uint2 p;
            p.x = (uint)f2bf(acc2[0][r]) | ((uint)f2bf(acc2[1][r]) << 16);
            p.y = (uint)f2bf(acc2[2][r]) | ((uint)f2bf(acc2[3][r]) << 16);
            *(uint2*)&SC[(g * 4 + r) * 80 + l15 * 4] = p;
        }

        // ---- step 4: scal for next batch -> sScal[buf^1] ----
        if (lane < 16) {
            const float dx = xr0 - xc0, dy = xr1 - xc1, dz = xr2 - xc2;
            const float r2 = dx * dx + dy * dy;
            const float rdv = r2 + dz * dz;
            const float inv = (r2 > 0.f) ? (1.f / r2) : 0.f;
            const float c2  = (r2 > 0.f) ? ((dx * dx - dy * dy) * inv) : 1.f;
            const float sn2 = 2.f * dx * dy * inv;
            const float phi = atan2f(dz, sqrtf(r2));
            float4 sc = {rdv, rdv * c2, rdv * sn2, rdv * phi};
            *(float4*)&sScal[wave][buf ^ 1][lane][0] = sc;
        }

        // ---- step 5: w-MLP (EF -> s1 -> scalar w) ----
        f32x4 acc3[4];
#pragma unroll
        for (int t = 0; t < 4; ++t) acc3[t] = (f32x4){wb1v[t], wb1v[t], wb1v[t], wb1v[t]};
#pragma unroll
        for (int kc = 0; kc < 2; ++kc) {
            bf16x8 a = *(const bf16x8*)&SC[l15 * 80 + kc * 32 + g * 8];
#pragma unroll
            for (int t = 0; t < 4; ++t)
                acc3[t] = __builtin_amdgcn_mfma_f32_16x16x32_bf16(
                    a, *(const bf16x8*)&sWB[(24 + kc * 4 + t) * 512 + lane * 8], acc3[t], 0, 0, 0);
        }
        float wfin[4];
#pragma unroll
        for (int r = 0; r < 4; ++r) {
            float p = fmaxf(acc3[0][r], 0.f) * w2v[0];
            p = fmaf(fmaxf(acc3[1][r], 0.f), w2v[1], p);
            p = fmaf(fmaxf(acc3[2][r], 0.f), w2v[2], p);
            p = fmaf(fmaxf(acc3[3][r], 0.f), w2v[3], p);
            wfin[r] = p;
        }
#pragma unroll
        for (int m = 1; m < 16; m <<= 1) {
#pragma unroll
            for (int r = 0; r < 4; ++r) wfin[r] += __shfl_xor(wfin[r], m);
        }
#pragma unroll
        for (int r = 0; r < 4; ++r) wfin[r] += wb2v;

        // ---- step 6: run-flush (rows sorted => long runs), uses sScal[buf] ----
#pragma unroll
        for (int e = 0; e < 16; ++e) {
            const int row_e = __shfl(rowv, e);
            const float efv = bf2f(SC[e * 80 + l15 * 4 + g]);   // ef[e][lane]
            const float wE = __shfl(wfin[e & 3], (e >> 2) * 16);
            if (row_e != cur_row) {
                if (cur_row >= 0) {
                    unsafeAtomicAdd(&agg[(size_t)cur_row * 64 + lane], carry);
                    if (lane < 3) unsafeAtomicAdd(&vsum[cur_row * 4 + lane], carryv);
                }
                cur_row = row_e; carry = 0.f; carryv = 0.f;
            }
            carry += efv;
            if (lane < 3) carryv = fmaf(sScal[wave][buf][e][1 + lane], wE, carryv);
        }

        // ---- rotate pipeline ----
        rowv = rv2;
        a0 = n0; a1 = n1; a2 = n2; a3 = n3;
        rc2 = rc3;
        buf ^= 1;
    }
    if (cur_row >= 0) {
        unsafeAtomicAdd(&agg[(size_t)cur_row * 64 + lane], carry);
        if (lane < 3) unsafeAtomicAdd(&vsum[cur_row * 4 + lane], carryv);
    }
}

// ---------------- node kernel: MFMA residual MLP + v normalize ----------------
__global__ __launch_bounds__(256, 2) void node_kernel(
    const ushort* __restrict__ hembb, const float* __restrict__ agg,
    const float* __restrict__ nW1, const float* __restrict__ nb1,
    const float* __restrict__ nW2, const float* __restrict__ nb2,
    const float* __restrict__ vsum, const int* __restrict__ csr,
    float* __restrict__ outh, float* __restrict__ outv)
{
    __shared__ ushort sT1[4][16 * 80];

    const int tid = threadIdx.x;
    const int wave = tid >> 6, lane = tid & 63;
    const int l15 = lane & 15, g = lane >> 4;

    bf16x8 W1f[4][4], W2f[2][4];
#pragma unroll
    for (int kc = 0; kc < 4; ++kc)
#pragma unroll
        for (int t = 0; t < 4; ++t) {
            bf16x8 f;
#pragma unroll
            for (int b = 0; b < 8; ++b) {
                int k = kc * 32 + g * 8 + b;
                f[b] = (short)f2bf(nW1[k * 64 + t * 16 + l15]);
            }
            W1f[kc][t] = f;
        }
#pragma unroll
    for (int kc = 0; kc < 2; ++kc)
#pragma unroll
        for (int t = 0; t < 4; ++t) {
            bf16x8 f;
#pragma unroll
            for (int b = 0; b < 8; ++b) {
                int s = kc * 32 + g * 8 + b;
                int j = (s >> 2) + (s & 3) * 16;
                f[b] = (short)f2bf(nW2[j * 64 + t * 16 + l15]);
            }
            W2f[kc][t] = f;
        }
    float b1v[4], b2v[4];
#pragma unroll
    for (int t = 0; t < 4; ++t) { b1v[t] = nb1[t * 16 + l15]; b2v[t] = nb2[t * 16 + l15]; }

    ushort* T1 = sT1[wave];
    const int nwaves = gridDim.x * 4;
    const int ntiles = NN / 16;   // 6250

    for (int tile = blockIdx.x * 4 + wave; tile < ntiles; tile += nwaves) {
        const int nb = tile * 16;

        f32x4 acc[4];
#pragma unroll
        for (int t = 0; t < 4; ++t) acc[t] = (f32x4){b1v[t], b1v[t], b1v[t], b1v[t]};
#pragma unroll
        for (int kc = 0; kc < 2; ++kc) {
            bf16x8 a = *(const bf16x8*)&hembb[(size_t)(nb + l15) * 64 + kc * 32 + g * 8];
#pragma unroll
            for (int t = 0; t < 4; ++t)
                acc[t] = __builtin_amdgcn_mfma_f32_16x16x32_bf16(a, W1f[kc][t], acc[t], 0, 0, 0);
        }
#pragma unroll
        for (int kc = 2; kc < 4; ++kc) {
            const float4 f0 = *(const float4*)&agg[(size_t)(nb + l15) * 64 + (kc - 2) * 32 + g * 8];
            const float4 f1 = *(const float4*)&agg[(size_t)(nb + l15) * 64 + (kc - 2) * 32 + g * 8 + 4];
            bf16x8 a;
            a[0] = (short)f2bf(f0.x); a[1] = (short)f2bf(f0.y);
            a[2] = (short)f2bf(f0.z); a[3] = (short)f2bf(f0.w);
            a[4] = (short)f2bf(f1.x); a[5] = (short)f2bf(f1.y);
            a[6] = (short)f2bf(f1.z); a[7] = (short)f2bf(f1.w);
#pragma unroll
            for (int t = 0; t < 4; ++t)
                acc[t] = __builtin_amdgcn_mfma_f32_16x16x32_bf16(a, W1f[kc][t], acc[t], 0, 0, 0);
        }
#pragma unroll
        for (int r = 0; r < 4; ++r) {
            const float v0 = fmaxf(acc[0][r], 0.f), v1 = fmaxf(acc[1][r], 0.f);
            const float v2 = fmaxf(acc[2][r], 0.f), v3 = fmaxf(acc[3][r], 0.f);
            uint2 p;
            p.x = (uint)f2bf(v0) | ((uint)f2bf(v1) << 16);
            p.y = (uint)f2bf(v2) | ((uint)f2bf(v3) << 16);
            *(uint2*)&T1[(g * 4 + r) * 80 + l15 * 4] = p;
        }

        f32x4 acc2[4];
#pragma unroll
        for (int t = 0; t < 4; ++t) acc2[t] = (f32x4){b2v[t], b2v[t], b2v[t], b2v[t]};
#pragma unroll
        for (int kc = 0; kc < 2; ++kc) {
            bf16x8 a = *(const bf16x8*)&T1[l15 * 80 + kc * 32 + g * 8];
#pragma unroll
            for (int t = 0; t < 4; ++t)
                acc2[t] = __builtin_amdgcn_mfma_f32_16x16x32_bf16(a, W2f[kc][t], acc2[t], 0, 0, 0);
        }
#pragma unroll
        for (int r = 0; r < 4; ++r) {
#pragma unroll
            for (int t = 0; t < 4; ++t) {
                const size_t idx = (size_t)(nb + g * 4 + r) * 64 + t * 16 + l15;
                outh[idx] = bf2f(hembb[idx]) + acc2[t][r];
            }
        }

        if (g == 0) {
            const int n = nb + l15;
            const float c = fmaxf((float)(csr[n + 1] - csr[n]), 1.f);
            const float4 vs = *(const float4*)&vsum[n * 4];
            const float a0 = vs.x / c, a1 = vs.y / c, a2 = vs.z / c;
            const float nrm = fmaxf(sqrtf(a0 * a0 + a1 * a1 + a2 * a2), 1e-12f);
            outv[n * 3 + 0] = a0 / nrm;
            outv[n * 3 + 1] = a1 / nrm;
            outv[n * 3 + 2] = a2 / nrm;
        }
    }
}

extern "C" void kernel_launch(void* const* d_in, const int* in_sizes, int n_in,
                              void* d_out, int out_size, void* d_ws, size_t ws_size,
                              hipStream_t stream)
{
    const float* h    = (const float*)d_in[0];
    const float* x    = (const float*)d_in[1];
    const int*   ei   = (const int*)d_in[2];
    const float* embW = (const float*)d_in[3];
    const float* embB = (const float*)d_in[4];
    const float* eW1  = (const float*)d_in[5];
    const float* eb1  = (const float*)d_in[6];
    const float* eW2  = (const float*)d_in[7];
    const float* eb2  = (const float*)d_in[8];
    const float* nW1  = (const float*)d_in[9];
    const float* nb1  = (const float*)d_in[10];
    const float* nW2  = (const float*)d_in[11];
    const float* nb2  = (const float*)d_in[12];
    const float* wW1  = (const float*)d_in[13];
    const float* wb1  = (const float*)d_in[14];
    const float* wW2  = (const float*)d_in[15];
    const float* wb2  = (const float*)d_in[16];

    float* ws     = (float*)d_ws;
    ushort* hembb = (ushort*)ws;                        // N*64 bf16 (= N*32 floats)
    float* agg    = ws + (size_t)NN * 32;               // N*64
    float* vsum   = agg + (size_t)NN * 64;              // N*4
    int*   hist   = (int*)(vsum + (size_t)NN * 4);      // N
    int*   csr    = hist + NN;                          // N+1
    int*   cursor = csr + NN + 1;                       // N
    int*   bsum   = cursor + NN;                        // 256
    int*   boff   = bsum + NBLK_SCAN;                   // 256
    int2*  srt    = (int2*)(boff + NBLK_SCAN);          // E pairs

    float* outh = (float*)d_out;                        // N*64
    float* outx = outh + (size_t)NN * 64;               // N*3
    float* outv = outx + (size_t)NN * 3;                // N*3

    // zero agg, vsum, hist (contiguous)
    hipMemsetAsync(agg, 0, ((size_t)NN * 64 + NN * 4 + NN) * sizeof(float), stream);

    embed_kernel<<<NN * 64 / 256, 256, 0, stream>>>(h, embW, embB, hembb);
    hipMemcpyAsync(outx, x, (size_t)NN * 3 * sizeof(float), hipMemcpyDeviceToDevice, stream);

    hist_kernel<<<2048, 256, 0, stream>>>(ei, hist);
    scan_a<<<NBLK_SCAN, 256, 0, stream>>>(hist, bsum);
    scan_b<<<1, 64, 0, stream>>>(bsum, boff);
    scan_c<<<NBLK_SCAN, 256, 0, stream>>>(hist, boff, csr, cursor);
    scatter_kernel<<<2048, 256, 0, stream>>>(ei, cursor, srt);

    edge_kernel<<<1000, 256, 0, stream>>>(hembb, x, srt, eW1, eb1, eW2, eb2,
                                          wW1, wb1, wW2, wb2, agg, vsum);
    node_kernel<<<1563, 256, 0, stream>>>(hembb, agg, nW1, nb1, nW2, nb2,
                                          vsum, csr, outh, outv);
}

// Round 14
// 462.707 us; speedup vs baseline: 1.7088x; 1.7088x over previous
//
#include <hip/hip_runtime.h>
#include <math.h>

#define NN 100000
#define EE 1600000
#define NBLK_SCAN 256
#define CHUNK ((NN + NBLK_SCAN - 1) / NBLK_SCAN)   // 391

#define EMB_NB  25000                  // NN*64/256
#define HIST_NB 2048
#define COPY_NB 1172                   // ceil(NN*3/256)

typedef __attribute__((ext_vector_type(8))) short bf16x8;
typedef __attribute__((ext_vector_type(4))) float f32x4;

__device__ __forceinline__ ushort f2bf(float x) {
    uint u = __builtin_bit_cast(uint, x);
    u += 0x7fffu + ((u >> 16) & 1u);   // RNE
    return (ushort)(u >> 16);
}
__device__ __forceinline__ float bf2f(ushort u) {
    uint v = ((uint)u) << 16;
    return __builtin_bit_cast(float, v);
}

// ---------------- fused prep: embed | histogram | outx copy ----------------
__global__ __launch_bounds__(256) void prep_kernel(
    const float* __restrict__ h, const float* __restrict__ embW,
    const float* __restrict__ embB, ushort* __restrict__ hembb,
    const int* __restrict__ ei, int* __restrict__ hist,
    const float* __restrict__ x, float* __restrict__ outx)
{
    const int b = blockIdx.x, tid = threadIdx.x;
    if (b < EMB_NB) {
        // embed: h_emb = h @ emb_W + emb_b  (bf16 out)
        const int t = b * 256 + tid;
        const int n = t >> 6, j = t & 63;
        float acc = embB[j];
#pragma unroll
        for (int k = 0; k < 16; ++k)
            acc = fmaf(h[n * 16 + k], embW[k * 64 + j], acc);
        hembb[(size_t)n * 64 + j] = f2bf(acc);
    } else if (b < EMB_NB + HIST_NB) {
        // histogram of rows
        for (int e = (b - EMB_NB) * 256 + tid; e < EE; e += HIST_NB * 256)
            atomicAdd(&hist[ei[e]], 1);
    } else {
        // outx = x
        const int i = (b - EMB_NB - HIST_NB) * 256 + tid;
        if (i < NN * 3) outx[i] = x[i];
    }
}

// ---------------- sort: scan (3 kernels) ----------------
__global__ __launch_bounds__(256) void scan_a(const int* __restrict__ hist, int* __restrict__ bsum)
{
    __shared__ int red[256];
    const int b = blockIdx.x, t = threadIdx.x;
    const int start = b * CHUNK, end = min(NN, start + CHUNK);
    int s = 0;
    for (int i = start + t; i < end; i += 256) s += hist[i];
    red[t] = s; __syncthreads();
    for (int k = 128; k > 0; k >>= 1) { if (t < k) red[t] += red[t + k]; __syncthreads(); }
    if (t == 0) bsum[b] = red[0];
}

__global__ void scan_b(const int* __restrict__ bsum, int* __restrict__ boff)
{
    if (threadIdx.x == 0) {
        int acc = 0;
        for (int i = 0; i < NBLK_SCAN; ++i) { boff[i] = acc; acc += bsum[i]; }
    }
}

__global__ __launch_bounds__(256) void scan_c(
    const int* __restrict__ hist, const int* __restrict__ boff,
    int* __restrict__ csr, int* __restrict__ cursor)
{
    __shared__ int lds[CHUNK];
    const int b = blockIdx.x, t = threadIdx.x;
    const int start = b * CHUNK, end = min(NN, start + CHUNK), n = end - start;
    for (int i = t; i < n; i += 256) lds[i] = hist[start + i];
    __syncthreads();
    if (t == 0) {
        int acc = boff[b];
        for (int i = 0; i < n; ++i) { int v = lds[i]; lds[i] = acc; acc += v; }
        if (end == NN) csr[NN] = acc;   // == EE
    }
    __syncthreads();
    for (int i = t; i < n; i += 256) { csr[start + i] = lds[i]; cursor[start + i] = lds[i]; }
}

// ---------------- sort: scatter sorted (row,col) pairs ----------------
__global__ __launch_bounds__(256) void scatter_kernel(
    const int* __restrict__ ei, int* __restrict__ cursor, int2* __restrict__ srt)
{
    for (int e = blockIdx.x * 256 + threadIdx.x; e < EE; e += gridDim.x * 256) {
        const int row = ei[e];
        const int p = atomicAdd(&cursor[row], 1);
        srt[p] = make_int2(row, ei[EE + e]);
    }
}

// ---------------- edge kernel: MFMA edge MLP + w-MLP, software-pipelined ----------------
// EXACT r10 structure (208 us verified). 500 blocks x 8 waves; each wave owns 400
// consecutive sorted positions (25 batches of 16).
// Occupancy verdict (r5-r12): kernel needs ~128 arch VGPR (any cap below SPILLS:
//   (512,4)/(256,3) -> FETCH balloons 10x). 128 arch + ~128 AGPR = 256 unified/wave
//   -> 2 waves/SIMD, occupancy pinned ~22%. Accepted; ILP via cross-batch pipelining.
// Convert-pack micro-opts ABANDONED: r11 raw asm = wrong semantics (absmax 10.5),
//   r13 __float22bfloat162_rn + bit_cast = compile error. Manual f2bf is proven.
// MFMA layout (mfma_f32_16x16x32_bf16):
//   A frag: lane l holds A[l&15][(l>>4)*8 + b]
//   B frag: lane l holds B[(l>>4)*8 + b][l&15]
//   D:      lane l, reg r holds D[(l>>4)*4 + r][l&15]
// Activation LDS is k-permuted: storage s holds column j(s) = (s>>2) + (s&3)*16.
__global__ __launch_bounds__(512, 2) void edge_kernel(
    const ushort* __restrict__ hembb, const float* __restrict__ x,
    const int2* __restrict__ srt,
    const float* __restrict__ eW1, const float* __restrict__ eb1,
    const float* __restrict__ eW2, const float* __restrict__ eb2,
    const float* __restrict__ wW1, const float* __restrict__ wb1,
    const float* __restrict__ wW2, const float* __restrict__ wb2,
    float* __restrict__ agg, float* __restrict__ vsum)
{
    // B-fragments: 32 frags x (64 lanes x 8 ush) = 32 KB
    __shared__ ushort sWB[32 * 512];
    __shared__ ushort sS[8][1280];          // per-wave scratch: T1 then EF (overlaid)
    __shared__ float  sScal[8][2][16][4];   // ping-pong {rd, rd*c2, rd*s2, rd*phi}

    const int tid = threadIdx.x;
    const int wave = tid >> 6, lane = tid & 63;
    const int l15 = lane & 15, g = lane >> 4;

    // ---- one-time weight staging into LDS (split across waves) ----
#pragma unroll
    for (int q = 0; q < 2; ++q) {
        const int fi = wave * 2 + q;           // 0..15
        const int kc = fi >> 2, t = fi & 3;
        bf16x8 f;
#pragma unroll
        for (int b = 0; b < 8; ++b)
            f[b] = (short)f2bf(eW1[(kc * 32 + g * 8 + b) * 64 + t * 16 + l15]);
        *(bf16x8*)&sWB[fi * 512 + lane * 8] = f;
    }
    {
        const int kc = wave >> 2, t = wave & 3;
        bf16x8 f, fv;
#pragma unroll
        for (int b = 0; b < 8; ++b) {
            int s = kc * 32 + g * 8 + b;
            int j = (s >> 2) + (s & 3) * 16;   // permuted k
            f[b]  = (short)f2bf(eW2[j * 64 + t * 16 + l15]);
            fv[b] = (short)f2bf(wW1[j * 64 + t * 16 + l15]);
        }
        *(bf16x8*)&sWB[(16 + wave) * 512 + lane * 8] = f;
        *(bf16x8*)&sWB[(24 + wave) * 512 + lane * 8] = fv;
    }

    float b1v[4], b2v[4], wb1v[4], w2v[4], w128v[4];
#pragma unroll
    for (int t = 0; t < 4; ++t) {
        b1v[t]   = eb1[t * 16 + l15];
        b2v[t]   = eb2[t * 16 + l15];
        wb1v[t]  = wb1[t * 16 + l15];
        w2v[t]   = wW2[t * 16 + l15];
        w128v[t] = eW1[128 * 64 + t * 16 + l15];
    }
    const float wb2v = wb2[0];
    __syncthreads();   // weights visible to all waves; no block barriers after this

    ushort* SC = sS[wave];
    const int base = (blockIdx.x * 8 + wave) * 400;

    float carry = 0.f, carryv = 0.f;
    int cur_row = -1;

    // ---- prologue: batch 0 prepared; batch 1 srt prefetched ----
    int rowv = 0;
    {
        int colv = 0;
        if (lane < 16) {
            const int2 rc = srt[base + lane];
            rowv = rc.x; colv = rc.y;
            const float dx = x[rowv * 3 + 0] - x[colv * 3 + 0];
            const float dy = x[rowv * 3 + 1] - x[colv * 3 + 1];
            const float dz = x[rowv * 3 + 2] - x[colv * 3 + 2];
            const float r2 = dx * dx + dy * dy;
            const float rdv = r2 + dz * dz;
            const float inv = (r2 > 0.f) ? (1.f / r2) : 0.f;
            const float c2  = (r2 > 0.f) ? ((dx * dx - dy * dy) * inv) : 1.f;
            const float sn2 = 2.f * dx * dy * inv;
            const float phi = atan2f(dz, sqrtf(r2));
            float4 sc = {rdv, rdv * c2, rdv * sn2, rdv * phi};
            *(float4*)&sScal[wave][0][lane][0] = sc;
        }
    }
    bf16x8 a0, a1, a2, a3;
    {
        int colv0 = 0;
        if (lane < 16) colv0 = srt[base + lane].y;   // L2-hot reload
        const int rowN = __shfl(rowv, l15);
        const int colN = __shfl(colv0, l15);
        a0 = *(const bf16x8*)&hembb[(size_t)rowN * 64 + g * 8];
        a1 = *(const bf16x8*)&hembb[(size_t)rowN * 64 + 32 + g * 8];
        a2 = *(const bf16x8*)&hembb[(size_t)colN * 64 + g * 8];
        a3 = *(const bf16x8*)&hembb[(size_t)colN * 64 + 32 + g * 8];
    }
    int2 rc2 = make_int2(0, 0);
    if (lane < 16) rc2 = srt[min(base + 16 + lane, EE - 1)];

    int buf = 0;

    for (int bt = 0; bt < 25; ++bt) {
        // ---- step 0: srt prefetch for bt+2 ----
        int2 rc3 = make_int2(0, 0);
        if (lane < 16) rc3 = srt[min(base + (bt + 2) * 16 + lane, EE - 1)];

        // ---- step 1: layer 1 (uses a0..a3, sScal[buf]) ----
        f32x4 acc[4];
#pragma unroll
        for (int t = 0; t < 4; ++t) acc[t] = (f32x4){b1v[t], b1v[t], b1v[t], b1v[t]};
#pragma unroll
        for (int t = 0; t < 4; ++t) {
            acc[t] = __builtin_amdgcn_mfma_f32_16x16x32_bf16(
                a0, *(const bf16x8*)&sWB[(0 * 4 + t) * 512 + lane * 8], acc[t], 0, 0, 0);
            acc[t] = __builtin_amdgcn_mfma_f32_16x16x32_bf16(
                a1, *(const bf16x8*)&sWB[(1 * 4 + t) * 512 + lane * 8], acc[t], 0, 0, 0);
            acc[t] = __builtin_amdgcn_mfma_f32_16x16x32_bf16(
                a2, *(const bf16x8*)&sWB[(2 * 4 + t) * 512 + lane * 8], acc[t], 0, 0, 0);
            acc[t] = __builtin_amdgcn_mfma_f32_16x16x32_bf16(
                a3, *(const bf16x8*)&sWB[(3 * 4 + t) * 512 + lane * 8], acc[t], 0, 0, 0);
        }
#pragma unroll
        for (int r = 0; r < 4; ++r) {
            const float rd_r = sScal[wave][buf][g * 4 + r][0];
#pragma unroll
            for (int t = 0; t < 4; ++t) acc[t][r] = fmaf(rd_r, w128v[t], acc[t][r]);
        }
        // relu + pack to T1 (permuted storage s = c*4 + t)
#pragma unroll
        for (int r = 0; r < 4; ++r) {
            const float v0 = fmaxf(acc[0][r], 0.f), v1 = fmaxf(acc[1][r], 0.f);
            const float v2 = fmaxf(acc[2][r], 0.f), v3 = fmaxf(acc[3][r], 0.f);
            uint2 p;
            p.x = (uint)f2bf(v0) | ((uint)f2bf(v1) << 16);
            p.y = (uint)f2bf(v2) | ((uint)f2bf(v3) << 16);
            *(uint2*)&SC[(g * 4 + r) * 80 + l15 * 4] = p;
        }

        // ---- step 2: issue next batch's gathers (A-frags + x) ----
        const int rv2 = rc2.x, cv2 = rc2.y;          // valid on lanes 0..15
        const int rowN2 = __shfl(rv2, l15);
        const int colN2 = __shfl(cv2, l15);
        const bf16x8 n0 = *(const bf16x8*)&hembb[(size_t)rowN2 * 64 + g * 8];
        const bf16x8 n1 = *(const bf16x8*)&hembb[(size_t)rowN2 * 64 + 32 + g * 8];
        const bf16x8 n2 = *(const bf16x8*)&hembb[(size_t)colN2 * 64 + g * 8];
        const bf16x8 n3 = *(const bf16x8*)&hembb[(size_t)colN2 * 64 + 32 + g * 8];
        float xr0 = 0.f, xr1 = 0.f, xr2 = 0.f, xc0 = 0.f, xc1 = 0.f, xc2 = 0.f;
        if (lane < 16) {
            xr0 = x[rv2 * 3 + 0]; xr1 = x[rv2 * 3 + 1]; xr2 = x[rv2 * 3 + 2];
            xc0 = x[cv2 * 3 + 0]; xc1 = x[cv2 * 3 + 1]; xc2 = x[cv2 * 3 + 2];
        }

        // ---- step 3: layer 2 (T1 -> EF, EF overlays T1) ----
        f32x4 acc2[4];
#pragma unroll
        for (int t = 0; t < 4; ++t) acc2[t] = (f32x4){b2v[t], b2v[t], b2v[t], b2v[t]};
#pragma unroll
        for (int kc = 0; kc < 2; ++kc) {
            bf16x8 a = *(const bf16x8*)&SC[l15 * 80 + kc * 32 + g * 8];
#pragma unroll
            for (int t = 0; t < 4; ++t)
                acc2[t] = __builtin_amdgcn_mfma_f32_16x16x32_bf16(
                    a, *(const bf16x8*)&sWB[(16 + kc * 4 + t) * 512 + lane * 8], acc2[t], 0, 0, 0);
        }
#pragma unroll
        for (int r = 0; r < 4; ++r) {
            uint2 p;
            p.x = (uint)f2bf(acc2[0][r]) | ((uint)f2bf(acc2[1][r]) << 16);
            p.y = (uint)f2bf(acc2[2][r]) | ((uint)f2bf(acc2[3][r]) << 16);
            *(uint2*)&SC[(g * 4 + r) * 80 + l15 * 4] = p;
        }

        // ---- step 4: scal for next batch -> sScal[buf^1] ----
        if (lane < 16) {
            const float dx = xr0 - xc0, dy = xr1 - xc1, dz = xr2 - xc2;
            const float r2 = dx * dx + dy * dy;
            const float rdv = r2 + dz * dz;
            const float inv = (r2 > 0.f) ? (1.f / r2) : 0.f;
            const float c2  = (r2 > 0.f) ? ((dx * dx - dy * dy) * inv) : 1.f;
            const float sn2 = 2.f * dx * dy * inv;
            const float phi = atan2f(dz, sqrtf(r2));
            float4 sc = {rdv, rdv * c2, rdv * sn2, rdv * phi};
            *(float4*)&sScal[wave][buf ^ 1][lane][0] = sc;
        }

        // ---- step 5: w-MLP (EF -> s1 -> scalar w) ----
        f32x4 acc3[4];
#pragma unroll
        for (int t = 0; t < 4; ++t) acc3[t] = (f32x4){wb1v[t], wb1v[t], wb1v[t], wb1v[t]};
#pragma unroll
        for (int kc = 0; kc < 2; ++kc) {
            bf16x8 a = *(const bf16x8*)&SC[l15 * 80 + kc * 32 + g * 8];
#pragma unroll
            for (int t = 0; t < 4; ++t)
                acc3[t] = __builtin_amdgcn_mfma_f32_16x16x32_bf16(
                    a, *(const bf16x8*)&sWB[(24 + kc * 4 + t) * 512 + lane * 8], acc3[t], 0, 0, 0);
        }
        float wfin[4];
#pragma unroll
        for (int r = 0; r < 4; ++r) {
            float p = fmaxf(acc3[0][r], 0.f) * w2v[0];
            p = fmaf(fmaxf(acc3[1][r], 0.f), w2v[1], p);
            p = fmaf(fmaxf(acc3[2][r], 0.f), w2v[2], p);
            p = fmaf(fmaxf(acc3[3][r], 0.f), w2v[3], p);
            wfin[r] = p;
        }
#pragma unroll
        for (int m = 1; m < 16; m <<= 1) {
#pragma unroll
            for (int r = 0; r < 4; ++r) wfin[r] += __shfl_xor(wfin[r], m);
        }
#pragma unroll
        for (int r = 0; r < 4; ++r) wfin[r] += wb2v;

        // ---- step 6: run-flush (rows sorted => long runs), uses sScal[buf] ----
#pragma unroll
        for (int e = 0; e < 16; ++e) {
            const int row_e = __shfl(rowv, e);
            const float efv = bf2f(SC[e * 80 + l15 * 4 + g]);   // ef[e][lane]
            const float wE = __shfl(wfin[e & 3], (e >> 2) * 16);
            if (row_e != cur_row) {
                if (cur_row >= 0) {
                    unsafeAtomicAdd(&agg[(size_t)cur_row * 64 + lane], carry);
                    if (lane < 3) unsafeAtomicAdd(&vsum[cur_row * 4 + lane], carryv);
                }
                cur_row = row_e; carry = 0.f; carryv = 0.f;
            }
            carry += efv;
            if (lane < 3) carryv = fmaf(sScal[wave][buf][e][1 + lane], wE, carryv);
        }

        // ---- rotate pipeline ----
        rowv = rv2;
        a0 = n0; a1 = n1; a2 = n2; a3 = n3;
        rc2 = rc3;
        buf ^= 1;
    }
    if (cur_row >= 0) {
        unsafeAtomicAdd(&agg[(size_t)cur_row * 64 + lane], carry);
        if (lane < 3) unsafeAtomicAdd(&vsum[cur_row * 4 + lane], carryv);
    }
}

// ---------------- node kernel: MFMA residual MLP + v normalize ----------------
__global__ __launch_bounds__(256, 2) void node_kernel(
    const ushort* __restrict__ hembb, const float* __restrict__ agg,
    const float* __restrict__ nW1, const float* __restrict__ nb1,
    const float* __restrict__ nW2, const float* __restrict__ nb2,
    const float* __restrict__ vsum, const int* __restrict__ csr,
    float* __restrict__ outh, float* __restrict__ outv)
{
    __shared__ ushort sT1[4][16 * 80];

    const int tid = threadIdx.x;
    const int wave = tid >> 6, lane = tid & 63;
    const int l15 = lane & 15, g = lane >> 4;

    bf16x8 W1f[4][4], W2f[2][4];
#pragma unroll
    for (int kc = 0; kc < 4; ++kc)
#pragma unroll
        for (int t = 0; t < 4; ++t) {
            bf16x8 f;
#pragma unroll
            for (int b = 0; b < 8; ++b) {
                int k = kc * 32 + g * 8 + b;
                f[b] = (short)f2bf(nW1[k * 64 + t * 16 + l15]);
            }
            W1f[kc][t] = f;
        }
#pragma unroll
    for (int kc = 0; kc < 2; ++kc)
#pragma unroll
        for (int t = 0; t < 4; ++t) {
            bf16x8 f;
#pragma unroll
            for (int b = 0; b < 8; ++b) {
                int s = kc * 32 + g * 8 + b;
                int j = (s >> 2) + (s & 3) * 16;
                f[b] = (short)f2bf(nW2[j * 64 + t * 16 + l15]);
            }
            W2f[kc][t] = f;
        }
    float b1v[4], b2v[4];
#pragma unroll
    for (int t = 0; t < 4; ++t) { b1v[t] = nb1[t * 16 + l15]; b2v[t] = nb2[t * 16 + l15]; }

    ushort* T1 = sT1[wave];
    const int nwaves = gridDim.x * 4;
    const int ntiles = NN / 16;   // 6250

    for (int tile = blockIdx.x * 4 + wave; tile < ntiles; tile += nwaves) {
        const int nb = tile * 16;

        f32x4 acc[4];
#pragma unroll
        for (int t = 0; t < 4; ++t) acc[t] = (f32x4){b1v[t], b1v[t], b1v[t], b1v[t]};
#pragma unroll
        for (int kc = 0; kc < 2; ++kc) {
            bf16x8 a = *(const bf16x8*)&hembb[(size_t)(nb + l15) * 64 + kc * 32 + g * 8];
#pragma unroll
            for (int t = 0; t < 4; ++t)
                acc[t] = __builtin_amdgcn_mfma_f32_16x16x32_bf16(a, W1f[kc][t], acc[t], 0, 0, 0);
        }
#pragma unroll
        for (int kc = 2; kc < 4; ++kc) {
            const float4 f0 = *(const float4*)&agg[(size_t)(nb + l15) * 64 + (kc - 2) * 32 + g * 8];
            const float4 f1 = *(const float4*)&agg[(size_t)(nb + l15) * 64 + (kc - 2) * 32 + g * 8 + 4];
            bf16x8 a;
            a[0] = (short)f2bf(f0.x); a[1] = (short)f2bf(f0.y);
            a[2] = (short)f2bf(f0.z); a[3] = (short)f2bf(f0.w);
            a[4] = (short)f2bf(f1.x); a[5] = (short)f2bf(f1.y);
            a[6] = (short)f2bf(f1.z); a[7] = (short)f2bf(f1.w);
#pragma unroll
            for (int t = 0; t < 4; ++t)
                acc[t] = __builtin_amdgcn_mfma_f32_16x16x32_bf16(a, W1f[kc][t], acc[t], 0, 0, 0);
        }
#pragma unroll
        for (int r = 0; r < 4; ++r) {
            const float v0 = fmaxf(acc[0][r], 0.f), v1 = fmaxf(acc[1][r], 0.f);
            const float v2 = fmaxf(acc[2][r], 0.f), v3 = fmaxf(acc[3][r], 0.f);
            uint2 p;
            p.x = (uint)f2bf(v0) | ((uint)f2bf(v1) << 16);
            p.y = (uint)f2bf(v2) | ((uint)f2bf(v3) << 16);
            *(uint2*)&T1[(g * 4 + r) * 80 + l15 * 4] = p;
        }

        f32x4 acc2[4];
#pragma unroll
        for (int t = 0; t < 4; ++t) acc2[t] = (f32x4){b2v[t], b2v[t], b2v[t], b2v[t]};
#pragma unroll
        for (int kc = 0; kc < 2; ++kc) {
            bf16x8 a = *(const bf16x8*)&T1[l15 * 80 + kc * 32 + g * 8];
#pragma unroll
            for (int t = 0; t < 4; ++t)
                acc2[t] = __builtin_amdgcn_mfma_f32_16x16x32_bf16(a, W2f[kc][t], acc2[t], 0, 0, 0);
        }
#pragma unroll
        for (int r = 0; r < 4; ++r) {
#pragma unroll
            for (int t = 0; t < 4; ++t) {
                const size_t idx = (size_t)(nb + g * 4 + r) * 64 + t * 16 + l15;
                outh[idx] = bf2f(hembb[idx]) + acc2[t][r];
            }
        }

        if (g == 0) {
            const int n = nb + l15;
            const float c = fmaxf((float)(csr[n + 1] - csr[n]), 1.f);
            const float4 vs = *(const float4*)&vsum[n * 4];
            const float a0 = vs.x / c, a1 = vs.y / c, a2 = vs.z / c;
            const float nrm = fmaxf(sqrtf(a0 * a0 + a1 * a1 + a2 * a2), 1e-12f);
            outv[n * 3 + 0] = a0 / nrm;
            outv[n * 3 + 1] = a1 / nrm;
            outv[n * 3 + 2] = a2 / nrm;
        }
    }
}

extern "C" void kernel_launch(void* const* d_in, const int* in_sizes, int n_in,
                              void* d_out, int out_size, void* d_ws, size_t ws_size,
                              hipStream_t stream)
{
    const float* h    = (const float*)d_in[0];
    const float* x    = (const float*)d_in[1];
    const int*   ei   = (const int*)d_in[2];
    const float* embW = (const float*)d_in[3];
    const float* embB = (const float*)d_in[4];
    const float* eW1  = (const float*)d_in[5];
    const float* eb1  = (const float*)d_in[6];
    const float* eW2  = (const float*)d_in[7];
    const float* eb2  = (const float*)d_in[8];
    const float* nW1  = (const float*)d_in[9];
    const float* nb1  = (const float*)d_in[10];
    const float* nW2  = (const float*)d_in[11];
    const float* nb2  = (const float*)d_in[12];
    const float* wW1  = (const float*)d_in[13];
    const float* wb1  = (const float*)d_in[14];
    const float* wW2  = (const float*)d_in[15];
    const float* wb2  = (const float*)d_in[16];

    float* ws     = (float*)d_ws;
    ushort* hembb = (ushort*)ws;                        // N*64 bf16 (= N*32 floats)
    float* agg    = ws + (size_t)NN * 32;               // N*64
    float* vsum   = agg + (size_t)NN * 64;              // N*4
    int*   hist   = (int*)(vsum + (size_t)NN * 4);      // N
    int*   csr    = hist + NN;                          // N+1
    int*   cursor = csr + NN + 1;                       // N
    int*   bsum   = cursor + NN;                        // 256
    int*   boff   = bsum + NBLK_SCAN;                   // 256
    int2*  srt    = (int2*)(boff + NBLK_SCAN);          // E pairs

    float* outh = (float*)d_out;                        // N*64
    float* outx = outh + (size_t)NN * 64;               // N*3
    float* outv = outx + (size_t)NN * 3;                // N*3

    // zero agg, vsum, hist (contiguous)
    (void)hipMemsetAsync(agg, 0, ((size_t)NN * 64 + NN * 4 + NN) * sizeof(float), stream);

    prep_kernel<<<EMB_NB + HIST_NB + COPY_NB, 256, 0, stream>>>(
        h, embW, embB, hembb, ei, hist, x, outx);

    scan_a<<<NBLK_SCAN, 256, 0, stream>>>(hist, bsum);
    scan_b<<<1, 64, 0, stream>>>(bsum, boff);
    scan_c<<<NBLK_SCAN, 256, 0, stream>>>(hist, boff, csr, cursor);
    scatter_kernel<<<2048, 256, 0, stream>>>(ei, cursor, srt);

    edge_kernel<<<500, 512, 0, stream>>>(hembb, x, srt, eW1, eb1, eW2, eb2,
                                         wW1, wb1, wW2, wb2, agg, vsum);
    node_kernel<<<1563, 256, 0, stream>>>(hembb, agg, nW1, nb1, nW2, nb2,
                                          vsum, csr, outh, outv);
}

// Round 15
// 453.836 us; speedup vs baseline: 1.7422x; 1.0195x over previous
//
#include <hip/hip_runtime.h>
#include <math.h>

#define NN 100000
#define EE 1600000
#define NBLK_SCAN 256
#define CHUNK ((NN + NBLK_SCAN - 1) / NBLK_SCAN)   // 391

#define EMB_NB  25000                  // NN*64/256
#define HIST_NB 2048
#define COPY_NB 1172                   // ceil(NN*3/256)

typedef __attribute__((ext_vector_type(8))) short bf16x8;
typedef __attribute__((ext_vector_type(4))) float f32x4;

__device__ __forceinline__ ushort f2bf(float x) {
    uint u = __builtin_bit_cast(uint, x);
    u += 0x7fffu + ((u >> 16) & 1u);   // RNE
    return (ushort)(u >> 16);
}
__device__ __forceinline__ float bf2f(ushort u) {
    uint v = ((uint)u) << 16;
    return __builtin_bit_cast(float, v);
}

// ---------------- fused prep: embed | histogram | outx copy ----------------
__global__ __launch_bounds__(256) void prep_kernel(
    const float* __restrict__ h, const float* __restrict__ embW,
    const float* __restrict__ embB, ushort* __restrict__ hembb,
    const int* __restrict__ ei, int* __restrict__ hist,
    const float* __restrict__ x, float* __restrict__ outx)
{
    const int b = blockIdx.x, tid = threadIdx.x;
    if (b < EMB_NB) {
        const int t = b * 256 + tid;
        const int n = t >> 6, j = t & 63;
        float acc = embB[j];
#pragma unroll
        for (int k = 0; k < 16; ++k)
            acc = fmaf(h[n * 16 + k], embW[k * 64 + j], acc);
        hembb[(size_t)n * 64 + j] = f2bf(acc);
    } else if (b < EMB_NB + HIST_NB) {
        for (int e = (b - EMB_NB) * 256 + tid; e < EE; e += HIST_NB * 256)
            atomicAdd(&hist[ei[e]], 1);
    } else {
        const int i = (b - EMB_NB - HIST_NB) * 256 + tid;
        if (i < NN * 3) outx[i] = x[i];
    }
}

// ---------------- sort: per-chunk reduce ----------------
__global__ __launch_bounds__(256) void scan_a(const int* __restrict__ hist, int* __restrict__ bsum)
{
    __shared__ int red[256];
    const int b = blockIdx.x, t = threadIdx.x;
    const int start = b * CHUNK, end = min(NN, start + CHUNK);
    int s = 0;
    for (int i = start + t; i < end; i += 256) s += hist[i];
    red[t] = s; __syncthreads();
    for (int k = 128; k > 0; k >>= 1) { if (t < k) red[t] += red[t + k]; __syncthreads(); }
    if (t == 0) bsum[b] = red[0];
}

// ---------------- sort: block-sum exclusive scan (parallel Hillis-Steele) ----------------
__global__ __launch_bounds__(256) void scan_b(const int* __restrict__ bsum, int* __restrict__ boff)
{
    __shared__ int s[256];
    const int t = threadIdx.x;
    const int a = bsum[t];
    s[t] = a; __syncthreads();
#pragma unroll
    for (int off = 1; off < 256; off <<= 1) {
        const int v = (t >= off) ? s[t - off] : 0;
        __syncthreads();
        s[t] += v;
        __syncthreads();
    }
    boff[t] = s[t] - a;   // exclusive
}

// ---------------- sort: per-chunk exclusive scan (parallel, 2 elem/thread) ----------------
__global__ __launch_bounds__(256) void scan_c(
    const int* __restrict__ hist, const int* __restrict__ boff,
    int* __restrict__ csr, int* __restrict__ cursor)
{
    __shared__ int s[512];
    const int b = blockIdx.x, t = threadIdx.x;
    const int start = b * CHUNK, end = min(NN, start + CHUNK), n = end - start;
    const int a0 = (t < n) ? hist[start + t] : 0;
    const int a1 = (256 + t < n) ? hist[start + 256 + t] : 0;
    s[t] = a0; s[256 + t] = a1;
    __syncthreads();
#pragma unroll
    for (int off = 1; off < 512; off <<= 1) {
        const int v0 = (t >= off) ? s[t - off] : 0;
        const int v1 = (256 + t >= off) ? s[256 + t - off] : 0;
        __syncthreads();
        s[t] += v0; s[256 + t] += v1;
        __syncthreads();
    }
    const int base = boff[b];
    if (t < n) {
        const int ex = base + s[t] - a0;
        csr[start + t] = ex; cursor[start + t] = ex;
    }
    if (256 + t < n) {
        const int ex = base + s[256 + t] - a1;
        csr[start + 256 + t] = ex; cursor[start + 256 + t] = ex;
    }
    if (end == NN && t == 0) csr[NN] = base + s[n - 1];   // == EE
}

// ---------------- sort: scatter sorted (row,col) pairs ----------------
__global__ __launch_bounds__(256) void scatter_kernel(
    const int* __restrict__ ei, int* __restrict__ cursor, int2* __restrict__ srt)
{
    for (int e = blockIdx.x * 256 + threadIdx.x; e < EE; e += gridDim.x * 256) {
        const int row = ei[e];
        const int p = atomicAdd(&cursor[row], 1);
        srt[p] = make_int2(row, ei[EE + e]);
    }
}

// ---------------- edge kernel: MFMA edge MLP + w-MLP, software-pipelined ----------------
// EXACT r10 structure (208 us verified). 500 blocks x 8 waves; each wave owns 400
// consecutive sorted positions (25 batches of 16).
// Occupancy verdict (r5-r12): kernel needs ~128 arch VGPR (any cap below SPILLS).
//   128 arch + ~128 AGPR = 256 unified/wave -> 2 waves/SIMD, occupancy pinned ~22%.
//   Accepted; ILP via cross-batch pipelining.
// MFMA layout (mfma_f32_16x16x32_bf16):
//   A frag: lane l holds A[l&15][(l>>4)*8 + b]
//   B frag: lane l holds B[(l>>4)*8 + b][l&15]
//   D:      lane l, reg r holds D[(l>>4)*4 + r][l&15]
// Activation LDS is k-permuted: storage s holds column j(s) = (s>>2) + (s&3)*16.
__global__ __launch_bounds__(512, 2) void edge_kernel(
    const ushort* __restrict__ hembb, const float* __restrict__ x,
    const int2* __restrict__ srt,
    const float* __restrict__ eW1, const float* __restrict__ eb1,
    const float* __restrict__ eW2, const float* __restrict__ eb2,
    const float* __restrict__ wW1, const float* __restrict__ wb1,
    const float* __restrict__ wW2, const float* __restrict__ wb2,
    float* __restrict__ agg, float* __restrict__ vsum)
{
    __shared__ ushort sWB[32 * 512];
    __shared__ ushort sS[8][1280];          // per-wave scratch: T1 then EF (overlaid)
    __shared__ float  sScal[8][2][16][4];   // ping-pong {rd, rd*c2, rd*s2, rd*phi}

    const int tid = threadIdx.x;
    const int wave = tid >> 6, lane = tid & 63;
    const int l15 = lane & 15, g = lane >> 4;

    // ---- one-time weight staging into LDS (split across waves) ----
#pragma unroll
    for (int q = 0; q < 2; ++q) {
        const int fi = wave * 2 + q;           // 0..15
        const int kc = fi >> 2, t = fi & 3;
        bf16x8 f;
#pragma unroll
        for (int b = 0; b < 8; ++b)
            f[b] = (short)f2bf(eW1[(kc * 32 + g * 8 + b) * 64 + t * 16 + l15]);
        *(bf16x8*)&sWB[fi * 512 + lane * 8] = f;
    }
    {
        const int kc = wave >> 2, t = wave & 3;
        bf16x8 f, fv;
#pragma unroll
        for (int b = 0; b < 8; ++b) {
            int s = kc * 32 + g * 8 + b;
            int j = (s >> 2) + (s & 3) * 16;   // permuted k
            f[b]  = (short)f2bf(eW2[j * 64 + t * 16 + l15]);
            fv[b] = (short)f2bf(wW1[j * 64 + t * 16 + l15]);
        }
        *(bf16x8*)&sWB[(16 + wave) * 512 + lane * 8] = f;
        *(bf16x8*)&sWB[(24 + wave) * 512 + lane * 8] = fv;
    }

    float b1v[4], b2v[4], wb1v[4], w2v[4], w128v[4];
#pragma unroll
    for (int t = 0; t < 4; ++t) {
        b1v[t]   = eb1[t * 16 + l15];
        b2v[t]   = eb2[t * 16 + l15];
        wb1v[t]  = wb1[t * 16 + l15];
        w2v[t]   = wW2[t * 16 + l15];
        w128v[t] = eW1[128 * 64 + t * 16 + l15];
    }
    const float wb2v = wb2[0];
    __syncthreads();   // weights visible to all waves; no block barriers after this

    ushort* SC = sS[wave];
    const int base = (blockIdx.x * 8 + wave) * 400;

    float carry = 0.f, carryv = 0.f;
    int cur_row = -1;

    // ---- prologue: batch 0 prepared; batch 1 srt prefetched ----
    int rowv = 0;
    {
        int colv = 0;
        if (lane < 16) {
            const int2 rc = srt[base + lane];
            rowv = rc.x; colv = rc.y;
            const float dx = x[rowv * 3 + 0] - x[colv * 3 + 0];
            const float dy = x[rowv * 3 + 1] - x[colv * 3 + 1];
            const float dz = x[rowv * 3 + 2] - x[colv * 3 + 2];
            const float r2 = dx * dx + dy * dy;
            const float rdv = r2 + dz * dz;
            const float inv = (r2 > 0.f) ? (1.f / r2) : 0.f;
            const float c2  = (r2 > 0.f) ? ((dx * dx - dy * dy) * inv) : 1.f;
            const float sn2 = 2.f * dx * dy * inv;
            const float phi = atan2f(dz, sqrtf(r2));
            float4 sc = {rdv, rdv * c2, rdv * sn2, rdv * phi};
            *(float4*)&sScal[wave][0][lane][0] = sc;
        }
    }
    bf16x8 a0, a1, a2, a3;
    {
        int colv0 = 0;
        if (lane < 16) colv0 = srt[base + lane].y;   // L2-hot reload
        const int rowN = __shfl(rowv, l15);
        const int colN = __shfl(colv0, l15);
        a0 = *(const bf16x8*)&hembb[(size_t)rowN * 64 + g * 8];
        a1 = *(const bf16x8*)&hembb[(size_t)rowN * 64 + 32 + g * 8];
        a2 = *(const bf16x8*)&hembb[(size_t)colN * 64 + g * 8];
        a3 = *(const bf16x8*)&hembb[(size_t)colN * 64 + 32 + g * 8];
    }
    int2 rc2 = make_int2(0, 0);
    if (lane < 16) rc2 = srt[min(base + 16 + lane, EE - 1)];

    int buf = 0;

    for (int bt = 0; bt < 25; ++bt) {
        // ---- step 0: srt prefetch for bt+2 ----
        int2 rc3 = make_int2(0, 0);
        if (lane < 16) rc3 = srt[min(base + (bt + 2) * 16 + lane, EE - 1)];

        // ---- step 1: layer 1 (uses a0..a3, sScal[buf]) ----
        f32x4 acc[4];
#pragma unroll
        for (int t = 0; t < 4; ++t) acc[t] = (f32x4){b1v[t], b1v[t], b1v[t], b1v[t]};
#pragma unroll
        for (int t = 0; t < 4; ++t) {
            acc[t] = __builtin_amdgcn_mfma_f32_16x16x32_bf16(
                a0, *(const bf16x8*)&sWB[(0 * 4 + t) * 512 + lane * 8], acc[t], 0, 0, 0);
            acc[t] = __builtin_amdgcn_mfma_f32_16x16x32_bf16(
                a1, *(const bf16x8*)&sWB[(1 * 4 + t) * 512 + lane * 8], acc[t], 0, 0, 0);
            acc[t] = __builtin_amdgcn_mfma_f32_16x16x32_bf16(
                a2, *(const bf16x8*)&sWB[(2 * 4 + t) * 512 + lane * 8], acc[t], 0, 0, 0);
            acc[t] = __builtin_amdgcn_mfma_f32_16x16x32_bf16(
                a3, *(const bf16x8*)&sWB[(3 * 4 + t) * 512 + lane * 8], acc[t], 0, 0, 0);
        }
#pragma unroll
        for (int r = 0; r < 4; ++r) {
            const float rd_r = sScal[wave][buf][g * 4 + r][0];
#pragma unroll
            for (int t = 0; t < 4; ++t) acc[t][r] = fmaf(rd_r, w128v[t], acc[t][r]);
        }
        // relu + pack to T1 (permuted storage s = c*4 + t)
#pragma unroll
        for (int r = 0; r < 4; ++r) {
            const float v0 = fmaxf(acc[0][r], 0.f), v1 = fmaxf(acc[1][r], 0.f);
            const float v2 = fmaxf(acc[2][r], 0.f), v3 = fmaxf(acc[3][r], 0.f);
            uint2 p;
            p.x = (uint)f2bf(v0) | ((uint)f2bf(v1) << 16);
            p.y = (uint)f2bf(v2) | ((uint)f2bf(v3) << 16);
            *(uint2*)&SC[(g * 4 + r) * 80 + l15 * 4] = p;
        }

        // ---- step 2: issue next batch's gathers (A-frags + x) ----
        const int rv2 = rc2.x, cv2 = rc2.y;          // valid on lanes 0..15
        const int rowN2 = __shfl(rv2, l15);
        const int colN2 = __shfl(cv2, l15);
        const bf16x8 n0 = *(const bf16x8*)&hembb[(size_t)rowN2 * 64 + g * 8];
        const bf16x8 n1 = *(const bf16x8*)&hembb[(size_t)rowN2 * 64 + 32 + g * 8];
        const bf16x8 n2 = *(const bf16x8*)&hembb[(size_t)colN2 * 64 + g * 8];
        const bf16x8 n3 = *(const bf16x8*)&hembb[(size_t)colN2 * 64 + 32 + g * 8];
        float xr0 = 0.f, xr1 = 0.f, xr2 = 0.f, xc0 = 0.f, xc1 = 0.f, xc2 = 0.f;
        if (lane < 16) {
            xr0 = x[rv2 * 3 + 0]; xr1 = x[rv2 * 3 + 1]; xr2 = x[rv2 * 3 + 2];
            xc0 = x[cv2 * 3 + 0]; xc1 = x[cv2 * 3 + 1]; xc2 = x[cv2 * 3 + 2];
        }

        // ---- step 3: layer 2 (T1 -> EF, EF overlays T1) ----
        f32x4 acc2[4];
#pragma unroll
        for (int t = 0; t < 4; ++t) acc2[t] = (f32x4){b2v[t], b2v[t], b2v[t], b2v[t]};
#pragma unroll
        for (int kc = 0; kc < 2; ++kc) {
            bf16x8 a = *(const bf16x8*)&SC[l15 * 80 + kc * 32 + g * 8];
#pragma unroll
            for (int t = 0; t < 4; ++t)
                acc2[t] = __builtin_amdgcn_mfma_f32_16x16x32_bf16(
                    a, *(const bf16x8*)&sWB[(16 + kc * 4 + t) * 512 + lane * 8], acc2[t], 0, 0, 0);
        }
#pragma unroll
        for (int r = 0; r < 4; ++r) {
            uint2 p;
            p.x = (uint)f2bf(acc2[0][r]) | ((uint)f2bf(acc2[1][r]) << 16);
            p.y = (uint)f2bf(acc2[2][r]) | ((uint)f2bf(acc2[3][r]) << 16);
            *(uint2*)&SC[(g * 4 + r) * 80 + l15 * 4] = p;
        }

        // ---- step 4: scal for next batch -> sScal[buf^1] ----
        if (lane < 16) {
            const float dx = xr0 - xc0, dy = xr1 - xc1, dz = xr2 - xc2;
            const float r2 = dx * dx + dy * dy;
            const float rdv = r2 + dz * dz;
            const float inv = (r2 > 0.f) ? (1.f / r2) : 0.f;
            const float c2  = (r2 > 0.f) ? ((dx * dx - dy * dy) * inv) : 1.f;
            const float sn2 = 2.f * dx * dy * inv;
            const float phi = atan2f(dz, sqrtf(r2));
            float4 sc = {rdv, rdv * c2, rdv * sn2, rdv * phi};
            *(float4*)&sScal[wave][buf ^ 1][lane][0] = sc;
        }

        // ---- step 5: w-MLP (EF -> s1 -> scalar w) ----
        f32x4 acc3[4];
#pragma unroll
        for (int t = 0; t < 4; ++t) acc3[t] = (f32x4){wb1v[t], wb1v[t], wb1v[t], wb1v[t]};
#pragma unroll
        for (int kc = 0; kc < 2; ++kc) {
            bf16x8 a = *(const bf16x8*)&SC[l15 * 80 + kc * 32 + g * 8];
#pragma unroll
            for (int t = 0; t < 4; ++t)
                acc3[t] = __builtin_amdgcn_mfma_f32_16x16x32_bf16(
                    a, *(const bf16x8*)&sWB[(24 + kc * 4 + t) * 512 + lane * 8], acc3[t], 0, 0, 0);
        }
        float wfin[4];
#pragma unroll
        for (int r = 0; r < 4; ++r) {
            float p = fmaxf(acc3[0][r], 0.f) * w2v[0];
            p = fmaf(fmaxf(acc3[1][r], 0.f), w2v[1], p);
            p = fmaf(fmaxf(acc3[2][r], 0.f), w2v[2], p);
            p = fmaf(fmaxf(acc3[3][r], 0.f), w2v[3], p);
            wfin[r] = p;
        }
#pragma unroll
        for (int m = 1; m < 16; m <<= 1) {
#pragma unroll
            for (int r = 0; r < 4; ++r) wfin[r] += __shfl_xor(wfin[r], m);
        }
#pragma unroll
        for (int r = 0; r < 4; ++r) wfin[r] += wb2v;

        // ---- step 6: run-flush (rows sorted => long runs), uses sScal[buf] ----
#pragma unroll
        for (int e = 0; e < 16; ++e) {
            const int row_e = __shfl(rowv, e);
            const float efv = bf2f(SC[e * 80 + l15 * 4 + g]);   // ef[e][lane]
            const float wE = __shfl(wfin[e & 3], (e >> 2) * 16);
            if (row_e != cur_row) {
                if (cur_row >= 0) {
                    unsafeAtomicAdd(&agg[(size_t)cur_row * 64 + lane], carry);
                    if (lane < 3) unsafeAtomicAdd(&vsum[cur_row * 4 + lane], carryv);
                }
                cur_row = row_e; carry = 0.f; carryv = 0.f;
            }
            carry += efv;
            if (lane < 3) carryv = fmaf(sScal[wave][buf][e][1 + lane], wE, carryv);
        }

        // ---- rotate pipeline ----
        rowv = rv2;
        a0 = n0; a1 = n1; a2 = n2; a3 = n3;
        rc2 = rc3;
        buf ^= 1;
    }
    if (cur_row >= 0) {
        unsafeAtomicAdd(&agg[(size_t)cur_row * 64 + lane], carry);
        if (lane < 3) unsafeAtomicAdd(&vsum[cur_row * 4 + lane], carryv);
    }
}

// ---------------- node kernel: MFMA residual MLP + v normalize ----------------
__global__ __launch_bounds__(256, 2) void node_kernel(
    const ushort* __restrict__ hembb, const float* __restrict__ agg,
    const float* __restrict__ nW1, const float* __restrict__ nb1,
    const float* __restrict__ nW2, const float* __restrict__ nb2,
    const float* __restrict__ vsum, const int* __restrict__ csr,
    float* __restrict__ outh, float* __restrict__ outv)
{
    __shared__ ushort sT1[4][16 * 80];

    const int tid = threadIdx.x;
    const int wave = tid >> 6, lane = tid & 63;
    const int l15 = lane & 15, g = lane >> 4;

    bf16x8 W1f[4][4], W2f[2][4];
#pragma unroll
    for (int kc = 0; kc < 4; ++kc)
#pragma unroll
        for (int t = 0; t < 4; ++t) {
            bf16x8 f;
#pragma unroll
            for (int b = 0; b < 8; ++b) {
                int k = kc * 32 + g * 8 + b;
                f[b] = (short)f2bf(nW1[k * 64 + t * 16 + l15]);
            }
            W1f[kc][t] = f;
        }
#pragma unroll
    for (int kc = 0; kc < 2; ++kc)
#pragma unroll
        for (int t = 0; t < 4; ++t) {
            bf16x8 f;
#pragma unroll
            for (int b = 0; b < 8; ++b) {
                int s = kc * 32 + g * 8 + b;
                int j = (s >> 2) + (s & 3) * 16;
                f[b] = (short)f2bf(nW2[j * 64 + t * 16 + l15]);
            }
            W2f[kc][t] = f;
        }
    float b1v[4], b2v[4];
#pragma unroll
    for (int t = 0; t < 4; ++t) { b1v[t] = nb1[t * 16 + l15]; b2v[t] = nb2[t * 16 + l15]; }

    ushort* T1 = sT1[wave];
    const int nwaves = gridDim.x * 4;
    const int ntiles = NN / 16;   // 6250

    for (int tile = blockIdx.x * 4 + wave; tile < ntiles; tile += nwaves) {
        const int nb = tile * 16;

        f32x4 acc[4];
#pragma unroll
        for (int t = 0; t < 4; ++t) acc[t] = (f32x4){b1v[t], b1v[t], b1v[t], b1v[t]};
#pragma unroll
        for (int kc = 0; kc < 2; ++kc) {
            bf16x8 a = *(const bf16x8*)&hembb[(size_t)(nb + l15) * 64 + kc * 32 + g * 8];
#pragma unroll
            for (int t = 0; t < 4; ++t)
                acc[t] = __builtin_amdgcn_mfma_f32_16x16x32_bf16(a, W1f[kc][t], acc[t], 0, 0, 0);
        }
#pragma unroll
        for (int kc = 2; kc < 4; ++kc) {
            const float4 f0 = *(const float4*)&agg[(size_t)(nb + l15) * 64 + (kc - 2) * 32 + g * 8];
            const float4 f1 = *(const float4*)&agg[(size_t)(nb + l15) * 64 + (kc - 2) * 32 + g * 8 + 4];
            bf16x8 a;
            a[0] = (short)f2bf(f0.x); a[1] = (short)f2bf(f0.y);
            a[2] = (short)f2bf(f0.z); a[3] = (short)f2bf(f0.w);
            a[4] = (short)f2bf(f1.x); a[5] = (short)f2bf(f1.y);
            a[6] = (short)f2bf(f1.z); a[7] = (short)f2bf(f1.w);
#pragma unroll
            for (int t = 0; t < 4; ++t)
                acc[t] = __builtin_amdgcn_mfma_f32_16x16x32_bf16(a, W1f[kc][t], acc[t], 0, 0, 0);
        }
#pragma unroll
        for (int r = 0; r < 4; ++r) {
            const float v0 = fmaxf(acc[0][r], 0.f), v1 = fmaxf(acc[1][r], 0.f);
            const float v2 = fmaxf(acc[2][r], 0.f), v3 = fmaxf(acc[3][r], 0.f);
            uint2 p;
            p.x = (uint)f2bf(v0) | ((uint)f2bf(v1) << 16);
            p.y = (uint)f2bf(v2) | ((uint)f2bf(v3) << 16);
            *(uint2*)&T1[(g * 4 + r) * 80 + l15 * 4] = p;
        }

        f32x4 acc2[4];
#pragma unroll
        for (int t = 0; t < 4; ++t) acc2[t] = (f32x4){b2v[t], b2v[t], b2v[t], b2v[t]};
#pragma unroll
        for (int kc = 0; kc < 2; ++kc) {
            bf16x8 a = *(const bf16x8*)&T1[l15 * 80 + kc * 32 + g * 8];
#pragma unroll
            for (int t = 0; t < 4; ++t)
                acc2[t] = __builtin_amdgcn_mfma_f32_16x16x32_bf16(a, W2f[kc][t], acc2[t], 0, 0, 0);
        }
#pragma unroll
        for (int r = 0; r < 4; ++r) {
#pragma unroll
            for (int t = 0; t < 4; ++t) {
                const size_t idx = (size_t)(nb + g * 4 + r) * 64 + t * 16 + l15;
                outh[idx] = bf2f(hembb[idx]) + acc2[t][r];
            }
        }

        if (g == 0) {
            const int n = nb + l15;
            const float c = fmaxf((float)(csr[n + 1] - csr[n]), 1.f);
            const float4 vs = *(const float4*)&vsum[n * 4];
            const float a0 = vs.x / c, a1 = vs.y / c, a2 = vs.z / c;
            const float nrm = fmaxf(sqrtf(a0 * a0 + a1 * a1 + a2 * a2), 1e-12f);
            outv[n * 3 + 0] = a0 / nrm;
            outv[n * 3 + 1] = a1 / nrm;
            outv[n * 3 + 2] = a2 / nrm;
        }
    }
}

extern "C" void kernel_launch(void* const* d_in, const int* in_sizes, int n_in,
                              void* d_out, int out_size, void* d_ws, size_t ws_size,
                              hipStream_t stream)
{
    const float* h    = (const float*)d_in[0];
    const float* x    = (const float*)d_in[1];
    const int*   ei   = (const int*)d_in[2];
    const float* embW = (const float*)d_in[3];
    const float* embB = (const float*)d_in[4];
    const float* eW1  = (const float*)d_in[5];
    const float* eb1  = (const float*)d_in[6];
    const float* eW2  = (const float*)d_in[7];
    const float* eb2  = (const float*)d_in[8];
    const float* nW1  = (const float*)d_in[9];
    const float* nb1  = (const float*)d_in[10];
    const float* nW2  = (const float*)d_in[11];
    const float* nb2  = (const float*)d_in[12];
    const float* wW1  = (const float*)d_in[13];
    const float* wb1  = (const float*)d_in[14];
    const float* wW2  = (const float*)d_in[15];
    const float* wb2  = (const float*)d_in[16];

    float* ws     = (float*)d_ws;
    ushort* hembb = (ushort*)ws;                        // N*64 bf16 (= N*32 floats)
    float* agg    = ws + (size_t)NN * 32;               // N*64
    float* vsum   = agg + (size_t)NN * 64;              // N*4
    int*   hist   = (int*)(vsum + (size_t)NN * 4);      // N
    int*   csr    = hist + NN;                          // N+1
    int*   cursor = csr + NN + 1;                       // N
    int*   bsum   = cursor + NN;                        // 256
    int*   boff   = bsum + NBLK_SCAN;                   // 256
    int2*  srt    = (int2*)(boff + NBLK_SCAN);          // E pairs

    float* outh = (float*)d_out;                        // N*64
    float* outx = outh + (size_t)NN * 64;               // N*3
    float* outv = outx + (size_t)NN * 3;                // N*3

    // zero agg, vsum, hist (contiguous)
    (void)hipMemsetAsync(agg, 0, ((size_t)NN * 64 + NN * 4 + NN) * sizeof(float), stream);

    prep_kernel<<<EMB_NB + HIST_NB + COPY_NB, 256, 0, stream>>>(
        h, embW, embB, hembb, ei, hist, x, outx);

    scan_a<<<NBLK_SCAN, 256, 0, stream>>>(hist, bsum);
    scan_b<<<1, 256, 0, stream>>>(bsum, boff);
    scan_c<<<NBLK_SCAN, 256, 0, stream>>>(hist, boff, csr, cursor);
    scatter_kernel<<<2048, 256, 0, stream>>>(ei, cursor, srt);

    edge_kernel<<<500, 512, 0, stream>>>(hembb, x, srt, eW1, eb1, eW2, eb2,
                                         wW1, wb1, wW2, wb2, agg, vsum);
    node_kernel<<<1563, 256, 0, stream>>>(hembb, agg, nW1, nb1, nW2, nb2,
                                          vsum, csr, outh, outv);
}